// Round 3
// baseline (460.053 us; speedup 1.0000x reference)
//
#include <hip/hip_runtime.h>
#include <hip/hip_bf16.h>
#include <stdint.h>

namespace {

constexpr float EPSF = 1e-5f;
constexpr float L2E = 1.4426950408889634f;
constexpr float QK_SCALE = 0.17677669529663687f;  // 32^-0.5
constexpr float SCALE2 = QK_SCALE * L2E;          // folded for exp2

typedef __attribute__((ext_vector_type(8))) short short8;
typedef __attribute__((ext_vector_type(4))) float f32x4;

__device__ __forceinline__ float lo16(uint32_t u) { return __uint_as_float(u << 16); }
__device__ __forceinline__ float hi16(uint32_t u) { return __uint_as_float(u & 0xFFFF0000u); }
__device__ __forceinline__ uint32_t pk2(float a, float b) {  // RNE pair -> v_cvt_pk_bf16_f32
  union { __hip_bfloat162 h; uint32_t u; } cv;
  cv.h.x = __float2bfloat16(a);
  cv.h.y = __float2bfloat16(b);
  return cv.u;
}
__device__ __forceinline__ float clip1(float v) { return fminf(fmaxf(v, -1.f), 1.f); }

// ---------------- K0: fold BN into transposed weights ----------------
__global__ void k0_fold(
    const float* __restrict__ Wq, const float* __restrict__ gq, const float* __restrict__ bq,
    const float* __restrict__ mq, const float* __restrict__ vq,
    const float* __restrict__ Wp, const float* __restrict__ gp, const float* __restrict__ bp,
    const float* __restrict__ mp, const float* __restrict__ vp,
    const float* __restrict__ W1, const float* __restrict__ g1, const float* __restrict__ b1,
    const float* __restrict__ m1, const float* __restrict__ v1,
    const float* __restrict__ W2, const float* __restrict__ g2, const float* __restrict__ b2,
    const float* __restrict__ m2, const float* __restrict__ v2,
    float* __restrict__ wqkvt, float* __restrict__ shq,
    float* __restrict__ wpt, float* __restrict__ shp,
    float* __restrict__ w1t, float* __restrict__ sh1,
    float* __restrict__ w2t, float* __restrict__ sh2) {
  int id = blockIdx.x * 256 + threadIdx.x;
  if (id < 65536) {
    int c = id >> 9, d = id & 511;
    wqkvt[id] = Wq[d * 128 + c] * (gq[d] * rsqrtf(vq[d] + EPSF));
  } else if (id < 98304) {
    int j = id - 65536; int d = j & 127, c2 = j >> 7;
    wpt[j] = Wp[d * 256 + c2] * (gp[d] * rsqrtf(vp[d] + EPSF));
  } else if (id < 131072) {
    int j = id - 98304; int d = j & 255, c = j >> 8;
    w1t[j] = W1[d * 128 + c] * (g1[d] * rsqrtf(v1[d] + EPSF));
  } else if (id < 163840) {
    int j = id - 131072; int d = j & 127, c2 = j >> 7;
    w2t[j] = W2[d * 256 + c2] * (g2[d] * rsqrtf(v2[d] + EPSF));
  } else if (id < 164864) {
    int j = id - 163840;
    if (j < 512)      shq[j] = bq[j] - mq[j] * (gq[j] * rsqrtf(vq[j] + EPSF));
    else if (j < 640) { int d = j - 512; shp[d] = bp[d] - mp[d] * (gp[d] * rsqrtf(vp[d] + EPSF)); }
    else if (j < 896) { int d = j - 640; sh1[d] = b1[d] - m1[d] * (g1[d] * rsqrtf(v1[d] + EPSF)); }
    else              { int d = j - 896; sh2[d] = b2[d] - m2[d] * (g2[d] * rsqrtf(v2[d] + EPSF)); }
  }
}

// ---------------- K1: qkv = BN(x_in @ Wqkv^T) -> qt (T), k (row-major), vt (T), bf16 ----------------
// qt: [bh][32 dims][1024 n]; kws: [bh][1024 n][32 dims]; vt: [bh][64 dims][1024 n]
__global__ __launch_bounds__(256) void k1_qkv(
    const float* __restrict__ x, const float* __restrict__ wt, const float* __restrict__ sh,
    uint16_t* __restrict__ qt, uint16_t* __restrict__ kws, uint16_t* __restrict__ vt) {
  __shared__ float xs[128][32];
  const int t = threadIdx.x;
  const int b = blockIdx.x >> 5, n0 = (blockIdx.x & 31) << 5;
  const float* xp = x + (size_t)b * (128 * 1024) + n0;
  {
    const int j = (t & 7) << 2;
    #pragma unroll
    for (int it = 0; it < 4; ++it) {
      const int c = (t >> 3) + (it << 5);
      *(float4*)&xs[c][j] = *(const float4*)(xp + c * 1024 + j);
    }
  }
  __syncthreads();
  const int d0 = (t & 63) << 3, j0 = (t >> 6) << 3;
  float acc[8][8];
  #pragma unroll
  for (int a = 0; a < 8; ++a)
    #pragma unroll
    for (int bb = 0; bb < 8; ++bb) acc[a][bb] = 0.f;
  for (int c = 0; c < 128; ++c) {
    const float4 xa = *(const float4*)&xs[c][j0];
    const float4 xb = *(const float4*)&xs[c][j0 + 4];
    const float4 wa = *(const float4*)(wt + c * 512 + d0);
    const float4 wb = *(const float4*)(wt + c * 512 + d0 + 4);
    const float xr[8] = {xa.x, xa.y, xa.z, xa.w, xb.x, xb.y, xb.z, xb.w};
    const float wr[8] = {wa.x, wa.y, wa.z, wa.w, wb.x, wb.y, wb.z, wb.w};
    #pragma unroll
    for (int dd = 0; dd < 8; ++dd)
      #pragma unroll
      for (int jj = 0; jj < 8; ++jj)
        acc[dd][jj] = fmaf(wr[dd], xr[jj], acc[dd][jj]);
  }
  float shr[8];
  #pragma unroll
  for (int dd = 0; dd < 8; ++dd) shr[dd] = sh[d0 + dd];
  const int h = d0 >> 7, r = d0 & 127;
  const size_t bh = (size_t)(b * 4 + h);
  if (r < 32) {
    uint16_t* qp = qt + bh * (32 * 1024) + (size_t)r * 1024 + n0 + j0;
    #pragma unroll
    for (int dd = 0; dd < 8; ++dd) {
      const float s = shr[dd];
      uint4 u = make_uint4(pk2(acc[dd][0] + s, acc[dd][1] + s), pk2(acc[dd][2] + s, acc[dd][3] + s),
                           pk2(acc[dd][4] + s, acc[dd][5] + s), pk2(acc[dd][6] + s, acc[dd][7] + s));
      *(uint4*)(qp + (size_t)dd * 1024) = u;
    }
  } else if (r < 64) {
    uint16_t* kp = kws + (bh * 1024 + n0 + j0) * 32 + (r - 32);
    #pragma unroll
    for (int jj = 0; jj < 8; ++jj) {
      uint4 u = make_uint4(pk2(acc[0][jj] + shr[0], acc[1][jj] + shr[1]),
                           pk2(acc[2][jj] + shr[2], acc[3][jj] + shr[3]),
                           pk2(acc[4][jj] + shr[4], acc[5][jj] + shr[5]),
                           pk2(acc[6][jj] + shr[6], acc[7][jj] + shr[7]));
      *(uint4*)(kp + (size_t)jj * 32) = u;
    }
  } else {
    uint16_t* vp = vt + bh * (64 * 1024) + (size_t)(r - 64) * 1024 + n0 + j0;
    #pragma unroll
    for (int dd = 0; dd < 8; ++dd) {
      const float s = shr[dd];
      uint4 u = make_uint4(pk2(acc[dd][0] + s, acc[dd][1] + s), pk2(acc[dd][2] + s, acc[dd][3] + s),
                           pk2(acc[dd][4] + s, acc[dd][5] + s), pk2(acc[dd][6] + s, acc[dd][7] + s));
      *(uint4*)(vp + (size_t)dd * 1024) = u;
    }
  }
}

// ---------------- K2: MFMA flash attention (no-max softmax, slot-relabeled PV) ----------------
// block = (b, h, 64 q-rows); 4 waves x 16 q each; 32-key steps.
__global__ __launch_bounds__(256) void k2_attn(
    const uint16_t* __restrict__ qt, const uint16_t* __restrict__ kws,
    const uint16_t* __restrict__ vt, const float* __restrict__ ab,
    float* __restrict__ ows) {
  __shared__ float biasr[1024];   // attn_biases row for this head, pre-scaled by log2(e)
  __shared__ float osm[4][16][68];
  const int t = threadIdx.x;
  // Bijective XCD-chunk swizzle: 2048 blocks, 8 XCDs -> each XCD gets 256
  // consecutive works => all 16 q-blocks of a (b,h) share one XCD's L2.
  const int blk = ((blockIdx.x & 7) << 8) | (blockIdx.x >> 3);
  const int qb = blk & 15, h = (blk >> 4) & 3, b = blk >> 6;
  for (int i = t; i < 1024; i += 256) biasr[i] = ab[(h << 10) + i] * L2E;
  __syncthreads();
  const int w = t >> 6, l = t & 63;
  const int c = l & 15, g = l >> 4;
  const int nq = (qb << 6) + (w << 4) + c;  // this lane's q index
  const size_t bh = (size_t)(b * 4 + h);
  const uint16_t* qtb = qt + bh * (32 * 1024);
  const uint16_t* kbp = kws + bh * (1024 * 32);
  const uint16_t* vtb = vt + bh * (64 * 1024) + (size_t)c * 1024 + (g << 2);
  // Q^T B-fragment: B[kdim=8g+j][q=c], once per wave
  short8 qf;
  #pragma unroll
  for (int j = 0; j < 8; ++j) qf[j] = (short)qtb[(size_t)((g << 3) + j) * 1024 + nq];
  const int qrow = nq >> 5, qcol = nq & 31;
  // per-lane bias column offsets (keys 4g+r and 16+4g+r within a 32-key step)
  int dc0[4], dc1[4];
  #pragma unroll
  for (int r = 0; r < 4; ++r) {
    int a0 = qcol - ((g << 2) + r);      dc0[r] = a0 < 0 ? -a0 : a0;
    int a1 = qcol - (16 + (g << 2) + r); dc1[r] = a1 < 0 ? -a1 : a1;
  }

  f32x4 o0 = {0.f, 0.f, 0.f, 0.f}, o1 = o0, o2 = o0, o3 = o0;
  float l_run = 0.f;

  union U { uint4 u; short8 s; };
  for (int kb = 0; kb < 1024; kb += 32) {
    // K A-fragments (coalesced): A[key=c][kdim=8g+j]
    U ka, kc;
    ka.u = *(const uint4*)(kbp + (size_t)(kb + c) * 32 + (g << 3));
    kc.u = *(const uint4*)(kbp + (size_t)(kb + 16 + c) * 32 + (g << 3));
    // V^T A-fragments with relabeled k-slots: slot(g,j) -> key kb+4g+j (j<4), kb+16+4g+j-4 (j>=4)
    const uint16_t* vp = vtb + kb;
    uint2 lo0 = *(const uint2*)(vp);                 uint2 hi0 = *(const uint2*)(vp + 16);
    uint2 lo1 = *(const uint2*)(vp + 16 * 1024);     uint2 hi1 = *(const uint2*)(vp + 16 * 1024 + 16);
    uint2 lo2 = *(const uint2*)(vp + 32 * 1024);     uint2 hi2 = *(const uint2*)(vp + 32 * 1024 + 16);
    uint2 lo3 = *(const uint2*)(vp + 48 * 1024);     uint2 hi3 = *(const uint2*)(vp + 48 * 1024 + 16);

    const f32x4 z = {0.f, 0.f, 0.f, 0.f};
    __builtin_amdgcn_s_setprio(1);
    f32x4 s0 = __builtin_amdgcn_mfma_f32_16x16x32_bf16(ka.s, qf, z, 0, 0, 0);
    f32x4 s1 = __builtin_amdgcn_mfma_f32_16x16x32_bf16(kc.s, qf, z, 0, 0, 0);
    __builtin_amdgcn_s_setprio(0);

    // p = exp2(s*scale*l2e + bias*l2e); krow constant within step
    int dr = qrow - (kb >> 5); dr = dr < 0 ? -dr : dr;
    const float* brow = biasr + (dr << 5);
    float p[8];
    float sum = 0.f;
    #pragma unroll
    for (int r = 0; r < 4; ++r) {
      p[r]     = exp2f(fmaf(s0[r], SCALE2, brow[dc0[r]]));
      p[4 + r] = exp2f(fmaf(s1[r], SCALE2, brow[dc1[r]]));
      sum += p[r] + p[4 + r];
    }
    l_run += sum;
    // P^T B-fragment: this lane's own 8 p-values, same slot labeling as A
    U pf;
    pf.u = make_uint4(pk2(p[0], p[1]), pk2(p[2], p[3]), pk2(p[4], p[5]), pk2(p[6], p[7]));
    U v0f, v1f, v2f, v3f;
    v0f.u = make_uint4(lo0.x, lo0.y, hi0.x, hi0.y);
    v1f.u = make_uint4(lo1.x, lo1.y, hi1.x, hi1.y);
    v2f.u = make_uint4(lo2.x, lo2.y, hi2.x, hi2.y);
    v3f.u = make_uint4(lo3.x, lo3.y, hi3.x, hi3.y);

    __builtin_amdgcn_s_setprio(1);
    o0 = __builtin_amdgcn_mfma_f32_16x16x32_bf16(v0f.s, pf.s, o0, 0, 0, 0);
    o1 = __builtin_amdgcn_mfma_f32_16x16x32_bf16(v1f.s, pf.s, o1, 0, 0, 0);
    o2 = __builtin_amdgcn_mfma_f32_16x16x32_bf16(v2f.s, pf.s, o2, 0, 0, 0);
    o3 = __builtin_amdgcn_mfma_f32_16x16x32_bf16(v3f.s, pf.s, o3, 0, 0, 0);
    __builtin_amdgcn_s_setprio(0);
  }

  float ls = l_run;
  ls += __shfl_xor(ls, 16, 64);
  ls += __shfl_xor(ls, 32, 64);
  const float inv = 1.f / ls;
  #pragma unroll
  for (int i = 0; i < 4; ++i) {
    osm[w][c][(g << 2) + i]      = o0[i] * inv;
    osm[w][c][16 + (g << 2) + i] = o1[i] * inv;
    osm[w][c][32 + (g << 2) + i] = o2[i] * inv;
    osm[w][c][48 + (g << 2) + i] = o3[i] * inv;
  }
  __syncthreads();
  const int q2 = l >> 2, dg = l & 3;
  const float4 r0 = *(const float4*)&osm[w][q2][dg * 16];
  const float4 r1 = *(const float4*)&osm[w][q2][dg * 16 + 4];
  const float4 r2 = *(const float4*)&osm[w][q2][dg * 16 + 8];
  const float4 r3 = *(const float4*)&osm[w][q2][dg * 16 + 12];
  float* op = ows + ((size_t)b * 1024 + (qb << 6) + (w << 4) + q2) * 256 + (h << 6) + dg * 16;
  *(float4*)(op)      = r0;
  *(float4*)(op + 4)  = r1;
  *(float4*)(op + 8)  = r2;
  *(float4*)(op + 12) = r3;
}

// ---------------- K3: x1 = x_in + BN(hardtanh(o) @ Wproj^T) ----------------
__global__ __launch_bounds__(256) void k3_proj(
    const float* __restrict__ ows, const float* __restrict__ x,
    const float* __restrict__ wt, const float* __restrict__ sh,
    float* __restrict__ x1) {
  __shared__ float os[256][36];
  const int t = threadIdx.x;
  const int b = blockIdx.x >> 5, n0 = (blockIdx.x & 31) << 5;
  {
    const int c0 = (t & 63) << 2;
    #pragma unroll
    for (int it = 0; it < 8; ++it) {
      const int j = (t >> 6) + (it << 2);
      float4 v4 = *(const float4*)(ows + ((size_t)b * 1024 + n0 + j) * 256 + c0);
      os[c0][j] = clip1(v4.x); os[c0 + 1][j] = clip1(v4.y);
      os[c0 + 2][j] = clip1(v4.z); os[c0 + 3][j] = clip1(v4.w);
    }
  }
  __syncthreads();
  const int d0 = (t & 31) << 2, j0 = (t >> 5) << 2;
  float acc[4][4];
  #pragma unroll
  for (int a = 0; a < 4; ++a)
    #pragma unroll
    for (int bb = 0; bb < 4; ++bb) acc[a][bb] = 0.f;
  for (int c2 = 0; c2 < 256; ++c2) {
    const float4 ov = *(const float4*)&os[c2][j0];
    const float4 wv = *(const float4*)(wt + c2 * 128 + d0);
    const float o_[4] = {ov.x, ov.y, ov.z, ov.w};
    const float w_[4] = {wv.x, wv.y, wv.z, wv.w};
    #pragma unroll
    for (int dd = 0; dd < 4; ++dd)
      #pragma unroll
      for (int jj = 0; jj < 4; ++jj)
        acc[dd][jj] = fmaf(w_[dd], o_[jj], acc[dd][jj]);
  }
  float res[4][4];
  #pragma unroll
  for (int dd = 0; dd < 4; ++dd) {
    const float shv = sh[d0 + dd];
    const float4 xv = *(const float4*)(x + ((size_t)b * 128 + d0 + dd) * 1024 + n0 + j0);
    res[dd][0] = acc[dd][0] + shv + xv.x;
    res[dd][1] = acc[dd][1] + shv + xv.y;
    res[dd][2] = acc[dd][2] + shv + xv.z;
    res[dd][3] = acc[dd][3] + shv + xv.w;
  }
  #pragma unroll
  for (int jj = 0; jj < 4; ++jj) {
    *(float4*)(x1 + ((size_t)b * 1024 + n0 + j0 + jj) * 128 + d0) =
        make_float4(res[0][jj], res[1][jj], res[2][jj], res[3][jj]);
  }
}

// ---------------- K4: h1 = hardtanh(BN(x1 @ Wf1^T)) -> bf16 ----------------
__global__ __launch_bounds__(256) void k4_f1(
    const float* __restrict__ x1, const float* __restrict__ wt, const float* __restrict__ sh,
    uint16_t* __restrict__ h1) {
  __shared__ float xs[128][36];
  const int t = threadIdx.x;
  const int b = blockIdx.x >> 5, n0 = (blockIdx.x & 31) << 5;
  {
    const int c0 = (t & 31) << 2;
    #pragma unroll
    for (int it = 0; it < 4; ++it) {
      const int j = (t >> 5) + (it << 3);
      float4 v4 = *(const float4*)(x1 + ((size_t)b * 1024 + n0 + j) * 128 + c0);
      xs[c0][j] = v4.x; xs[c0 + 1][j] = v4.y; xs[c0 + 2][j] = v4.z; xs[c0 + 3][j] = v4.w;
    }
  }
  __syncthreads();
  const int d0 = (t & 63) << 2, j0 = (t >> 6) << 3;
  float acc[4][8];
  #pragma unroll
  for (int a = 0; a < 4; ++a)
    #pragma unroll
    for (int bb = 0; bb < 8; ++bb) acc[a][bb] = 0.f;
  for (int c = 0; c < 128; ++c) {
    const float4 xa = *(const float4*)&xs[c][j0];
    const float4 xb = *(const float4*)&xs[c][j0 + 4];
    const float4 wv = *(const float4*)(wt + c * 256 + d0);
    const float xr[8] = {xa.x, xa.y, xa.z, xa.w, xb.x, xb.y, xb.z, xb.w};
    const float w_[4] = {wv.x, wv.y, wv.z, wv.w};
    #pragma unroll
    for (int dd = 0; dd < 4; ++dd)
      #pragma unroll
      for (int jj = 0; jj < 8; ++jj)
        acc[dd][jj] = fmaf(w_[dd], xr[jj], acc[dd][jj]);
  }
  float shr[4];
  #pragma unroll
  for (int dd = 0; dd < 4; ++dd) shr[dd] = sh[d0 + dd];
  #pragma unroll
  for (int jj = 0; jj < 8; ++jj) {
    const int n = n0 + j0 + jj;
    const float v0 = clip1(acc[0][jj] + shr[0]);
    const float v1 = clip1(acc[1][jj] + shr[1]);
    const float v2 = clip1(acc[2][jj] + shr[2]);
    const float v3 = clip1(acc[3][jj] + shr[3]);
    *(uint2*)(h1 + ((size_t)b * 1024 + n) * 256 + d0) = make_uint2(pk2(v0, v1), pk2(v2, v3));
  }
}

// ---------------- K5: out[b][c][n] = x1 + BN(h1 @ Wf2^T) ----------------
__global__ __launch_bounds__(256) void k5_f2(
    const uint16_t* __restrict__ h1, const float* __restrict__ x1,
    const float* __restrict__ wt, const float* __restrict__ sh,
    float* __restrict__ out) {
  __shared__ float hs[256][36];
  const int t = threadIdx.x;
  const int b = blockIdx.x >> 5, n0 = (blockIdx.x & 31) << 5;
  {
    const int c0 = (t & 31) << 3;
    #pragma unroll
    for (int it = 0; it < 4; ++it) {
      const int j = (t >> 5) + (it << 3);
      uint4 u = *(const uint4*)(h1 + ((size_t)b * 1024 + n0 + j) * 256 + c0);
      hs[c0][j] = lo16(u.x); hs[c0 + 1][j] = hi16(u.x);
      hs[c0 + 2][j] = lo16(u.y); hs[c0 + 3][j] = hi16(u.y);
      hs[c0 + 4][j] = lo16(u.z); hs[c0 + 5][j] = hi16(u.z);
      hs[c0 + 6][j] = lo16(u.w); hs[c0 + 7][j] = hi16(u.w);
    }
  }
  __syncthreads();
  const int d0 = (t & 31) << 2, j0 = (t >> 5) << 2;
  float acc[4][4];
  #pragma unroll
  for (int a = 0; a < 4; ++a)
    #pragma unroll
    for (int bb = 0; bb < 4; ++bb) acc[a][bb] = 0.f;
  for (int c2 = 0; c2 < 256; ++c2) {
    const float4 hv = *(const float4*)&hs[c2][j0];
    const float4 wv = *(const float4*)(wt + c2 * 128 + d0);
    const float h_[4] = {hv.x, hv.y, hv.z, hv.w};
    const float w_[4] = {wv.x, wv.y, wv.z, wv.w};
    #pragma unroll
    for (int dd = 0; dd < 4; ++dd)
      #pragma unroll
      for (int jj = 0; jj < 4; ++jj)
        acc[dd][jj] = fmaf(w_[dd], h_[jj], acc[dd][jj]);
  }
  float shr[4];
  #pragma unroll
  for (int dd = 0; dd < 4; ++dd) shr[dd] = sh[d0 + dd];
  float res[4][4];
  #pragma unroll
  for (int jj = 0; jj < 4; ++jj) {
    const float4 xv = *(const float4*)(x1 + ((size_t)b * 1024 + n0 + j0 + jj) * 128 + d0);
    res[0][jj] = acc[0][jj] + shr[0] + xv.x;
    res[1][jj] = acc[1][jj] + shr[1] + xv.y;
    res[2][jj] = acc[2][jj] + shr[2] + xv.z;
    res[3][jj] = acc[3][jj] + shr[3] + xv.w;
  }
  #pragma unroll
  for (int dd = 0; dd < 4; ++dd) {
    *(float4*)(out + ((size_t)b * 128 + d0 + dd) * 1024 + n0 + j0) =
        make_float4(res[dd][0], res[dd][1], res[dd][2], res[dd][3]);
  }
}

}  // namespace

extern "C" void kernel_launch(void* const* d_in, const int* in_sizes, int n_in,
                              void* d_out, int out_size, void* d_ws, size_t ws_size,
                              hipStream_t stream) {
  const float* x  = (const float*)d_in[0];
  const float* Wq = (const float*)d_in[1];
  const float* gq = (const float*)d_in[2];
  const float* bq = (const float*)d_in[3];
  const float* mq = (const float*)d_in[4];
  const float* vq = (const float*)d_in[5];
  const float* Wp = (const float*)d_in[6];
  const float* gp = (const float*)d_in[7];
  const float* bp = (const float*)d_in[8];
  const float* mp = (const float*)d_in[9];
  const float* vp = (const float*)d_in[10];
  const float* W1 = (const float*)d_in[11];
  const float* g1 = (const float*)d_in[12];
  const float* b1 = (const float*)d_in[13];
  const float* m1 = (const float*)d_in[14];
  const float* v1 = (const float*)d_in[15];
  const float* W2 = (const float*)d_in[16];
  const float* g2 = (const float*)d_in[17];
  const float* b2 = (const float*)d_in[18];
  const float* m2 = (const float*)d_in[19];
  const float* v2 = (const float*)d_in[20];
  const float* ab = (const float*)d_in[21];
  float* out = (float*)d_out;

  char* ws = (char*)d_ws;
  uint16_t* qt  = (uint16_t*)(ws);                 // 8 MiB  [bh][32][1024]
  uint16_t* kwsp= (uint16_t*)(ws + (8ull << 20));  // 8 MiB  [bh][1024][32]
  uint16_t* vt  = (uint16_t*)(ws + (16ull << 20)); // 16 MiB [bh][64][1024]
  float*    ows = (float*)(ws + (32ull << 20));    // 32 MiB
  float*    x1  = (float*)(ws + (64ull << 20));    // 16 MiB
  uint16_t* h1  = (uint16_t*)(ws);                 // reuse qt/kws region (dead after K2)
  float* wqkvt = (float*)(ws + (80ull << 20));
  float* shq   = wqkvt + 65536;
  float* wpt   = shq + 512;
  float* shp   = wpt + 32768;
  float* w1t   = shp + 128;
  float* sh1   = w1t + 32768;
  float* w2t   = sh1 + 256;
  float* sh2   = w2t + 32768;

  k0_fold<<<644, 256, 0, stream>>>(Wq, gq, bq, mq, vq, Wp, gp, bp, mp, vp,
                                   W1, g1, b1, m1, v1, W2, g2, b2, m2, v2,
                                   wqkvt, shq, wpt, shp, w1t, sh1, w2t, sh2);
  k1_qkv<<<1024, 256, 0, stream>>>(x, wqkvt, shq, qt, kwsp, vt);
  k2_attn<<<2048, 256, 0, stream>>>(qt, kwsp, vt, ab, ows);
  k3_proj<<<1024, 256, 0, stream>>>(ows, x, wpt, shp, x1);
  k4_f1<<<1024, 256, 0, stream>>>(x1, w1t, sh1, h1);
  k5_f2<<<1024, 256, 0, stream>>>(h1, x1, w2t, sh2, out);
  (void)in_sizes; (void)n_in; (void)out_size; (void)ws_size;
}

// Round 4
// 286.393 us; speedup vs baseline: 1.6064x; 1.6064x over previous
//
#include <hip/hip_runtime.h>
#include <hip/hip_bf16.h>
#include <stdint.h>

namespace {

constexpr float EPSF = 1e-5f;
constexpr float L2E = 1.4426950408889634f;
constexpr float QK_SCALE = 0.17677669529663687f;  // 32^-0.5
constexpr float SCALE2 = QK_SCALE * L2E;          // folded for exp2

typedef __attribute__((ext_vector_type(8))) short short8;
typedef __attribute__((ext_vector_type(4))) float f32x4;

__device__ __forceinline__ float lo16(uint32_t u) { return __uint_as_float(u << 16); }
__device__ __forceinline__ float hi16(uint32_t u) { return __uint_as_float(u & 0xFFFF0000u); }
__device__ __forceinline__ uint32_t pk2(float a, float b) {  // RNE pair -> v_cvt_pk_bf16_f32
  union { __hip_bfloat162 h; uint32_t u; } cv;
  cv.h.x = __float2bfloat16(a);
  cv.h.y = __float2bfloat16(b);
  return cv.u;
}
__device__ __forceinline__ float clip1(float v) { return fminf(fmaxf(v, -1.f), 1.f); }

// ---------------- K0: fold BN into transposed weights ----------------
__global__ void k0_fold(
    const float* __restrict__ Wq, const float* __restrict__ gq, const float* __restrict__ bq,
    const float* __restrict__ mq, const float* __restrict__ vq,
    const float* __restrict__ Wp, const float* __restrict__ gp, const float* __restrict__ bp,
    const float* __restrict__ mp, const float* __restrict__ vp,
    const float* __restrict__ W1, const float* __restrict__ g1, const float* __restrict__ b1,
    const float* __restrict__ m1, const float* __restrict__ v1,
    const float* __restrict__ W2, const float* __restrict__ g2, const float* __restrict__ b2,
    const float* __restrict__ m2, const float* __restrict__ v2,
    float* __restrict__ wqkvt, float* __restrict__ shq,
    float* __restrict__ wpt, float* __restrict__ shp,
    float* __restrict__ w1t, float* __restrict__ sh1,
    float* __restrict__ w2t, float* __restrict__ sh2) {
  int id = blockIdx.x * 256 + threadIdx.x;
  if (id < 65536) {
    int c = id >> 9, d = id & 511;
    wqkvt[id] = Wq[d * 128 + c] * (gq[d] * rsqrtf(vq[d] + EPSF));
  } else if (id < 98304) {
    int j = id - 65536; int d = j & 127, c2 = j >> 7;
    wpt[j] = Wp[d * 256 + c2] * (gp[d] * rsqrtf(vp[d] + EPSF));
  } else if (id < 131072) {
    int j = id - 98304; int d = j & 255, c = j >> 8;
    w1t[j] = W1[d * 128 + c] * (g1[d] * rsqrtf(v1[d] + EPSF));
  } else if (id < 163840) {
    int j = id - 131072; int d = j & 127, c2 = j >> 7;
    w2t[j] = W2[d * 256 + c2] * (g2[d] * rsqrtf(v2[d] + EPSF));
  } else if (id < 164864) {
    int j = id - 163840;
    if (j < 512)      shq[j] = bq[j] - mq[j] * (gq[j] * rsqrtf(vq[j] + EPSF));
    else if (j < 640) { int d = j - 512; shp[d] = bp[d] - mp[d] * (gp[d] * rsqrtf(vp[d] + EPSF)); }
    else if (j < 896) { int d = j - 640; sh1[d] = b1[d] - m1[d] * (g1[d] * rsqrtf(v1[d] + EPSF)); }
    else              { int d = j - 896; sh2[d] = b2[d] - m2[d] * (g2[d] * rsqrtf(v2[d] + EPSF)); }
  }
}

// ---------------- K1: qkv = BN(x_in @ Wqkv^T) -> qt (T), k (row-major), vt2 (permuted), bf16 ----
// qt: [bh][32 dims][1024 n]; kws: [bh][1024 n][32 dims]
// vt2: [bh][t:32][dt:4][g:4][c:16][j:8], element = V[key=32t+(j<4?4g+j:16+4g+j-4)][d=16dt+c]
__global__ __launch_bounds__(256) void k1_qkv(
    const float* __restrict__ x, const float* __restrict__ wt, const float* __restrict__ sh,
    uint16_t* __restrict__ qt, uint16_t* __restrict__ kws, uint16_t* __restrict__ vt) {
  __shared__ float xs[128][32];
  const int t = threadIdx.x;
  const int b = blockIdx.x >> 5, n0 = (blockIdx.x & 31) << 5;
  const float* xp = x + (size_t)b * (128 * 1024) + n0;
  {
    const int j = (t & 7) << 2;
    #pragma unroll
    for (int it = 0; it < 4; ++it) {
      const int c = (t >> 3) + (it << 5);
      *(float4*)&xs[c][j] = *(const float4*)(xp + c * 1024 + j);
    }
  }
  __syncthreads();
  const int d0 = (t & 63) << 3, j0 = (t >> 6) << 3;
  float acc[8][8];
  #pragma unroll
  for (int a = 0; a < 8; ++a)
    #pragma unroll
    for (int bb = 0; bb < 8; ++bb) acc[a][bb] = 0.f;
  for (int c = 0; c < 128; ++c) {
    const float4 xa = *(const float4*)&xs[c][j0];
    const float4 xb = *(const float4*)&xs[c][j0 + 4];
    const float4 wa = *(const float4*)(wt + c * 512 + d0);
    const float4 wb = *(const float4*)(wt + c * 512 + d0 + 4);
    const float xr[8] = {xa.x, xa.y, xa.z, xa.w, xb.x, xb.y, xb.z, xb.w};
    const float wr[8] = {wa.x, wa.y, wa.z, wa.w, wb.x, wb.y, wb.z, wb.w};
    #pragma unroll
    for (int dd = 0; dd < 8; ++dd)
      #pragma unroll
      for (int jj = 0; jj < 8; ++jj)
        acc[dd][jj] = fmaf(wr[dd], xr[jj], acc[dd][jj]);
  }
  float shr[8];
  #pragma unroll
  for (int dd = 0; dd < 8; ++dd) shr[dd] = sh[d0 + dd];
  const int h = d0 >> 7, r = d0 & 127;
  const size_t bh = (size_t)(b * 4 + h);
  if (r < 32) {
    uint16_t* qp = qt + bh * (32 * 1024) + (size_t)r * 1024 + n0 + j0;
    #pragma unroll
    for (int dd = 0; dd < 8; ++dd) {
      const float s = shr[dd];
      uint4 u = make_uint4(pk2(acc[dd][0] + s, acc[dd][1] + s), pk2(acc[dd][2] + s, acc[dd][3] + s),
                           pk2(acc[dd][4] + s, acc[dd][5] + s), pk2(acc[dd][6] + s, acc[dd][7] + s));
      *(uint4*)(qp + (size_t)dd * 1024) = u;
    }
  } else if (r < 64) {
    uint16_t* kp = kws + (bh * 1024 + n0 + j0) * 32 + (r - 32);
    #pragma unroll
    for (int jj = 0; jj < 8; ++jj) {
      uint4 u = make_uint4(pk2(acc[0][jj] + shr[0], acc[1][jj] + shr[1]),
                           pk2(acc[2][jj] + shr[2], acc[3][jj] + shr[3]),
                           pk2(acc[4][jj] + shr[4], acc[5][jj] + shr[5]),
                           pk2(acc[6][jj] + shr[6], acc[7][jj] + shr[7]));
      *(uint4*)(kp + (size_t)jj * 32) = u;
    }
  } else {
    // permuted-coalesced vt2
    const int dv0 = r - 64;                      // {0,8,...,56}
    const int dt = dv0 >> 4, c0 = dv0 & 15;      // c0 in {0,8}
    const int t32 = n0 >> 5;
    const int gA = (j0 >> 2) & 3, gB = gA + 1;
    const int jb = (j0 & 16) ? 4 : 0;
    uint16_t* vbase = vt + bh * 65536 + (size_t)(t32 * 4 + dt) * 512 + jb;
    #pragma unroll
    for (int dd = 0; dd < 8; ++dd) {
      const float s = shr[dd];
      *(uint2*)(vbase + gA * 128 + (c0 + dd) * 8) =
          make_uint2(pk2(acc[dd][0] + s, acc[dd][1] + s), pk2(acc[dd][2] + s, acc[dd][3] + s));
      *(uint2*)(vbase + gB * 128 + (c0 + dd) * 8) =
          make_uint2(pk2(acc[dd][4] + s, acc[dd][5] + s), pk2(acc[dd][6] + s, acc[dd][7] + s));
    }
  }
}

// ---------------- K2: MFMA flash attention (no-max softmax, coalesced permuted V) ----------------
// block = (b, h, 64 q-rows); 4 waves x 16 q each; 32-key steps.
__global__ __launch_bounds__(256) void k2_attn(
    const uint16_t* __restrict__ qt, const uint16_t* __restrict__ kws,
    const uint16_t* __restrict__ vt, const float* __restrict__ ab,
    float* __restrict__ ows) {
  __shared__ float biasr[1024];   // attn_biases row for this head, pre-scaled by log2(e)
  __shared__ float osm[4][16][68];
  const int t = threadIdx.x;
  // Bijective XCD-chunk swizzle: 2048 blocks, 8 XCDs -> each XCD gets 256
  // consecutive works => all 16 q-blocks of a (b,h) share one XCD's L2.
  const int blk = ((blockIdx.x & 7) << 8) | (blockIdx.x >> 3);
  const int qb = blk & 15, h = (blk >> 4) & 3, b = blk >> 6;
  for (int i = t; i < 1024; i += 256) biasr[i] = ab[(h << 10) + i] * L2E;
  __syncthreads();
  const int w = t >> 6, l = t & 63;
  const int c = l & 15, g = l >> 4;
  const int nq = (qb << 6) + (w << 4) + c;  // this lane's q index
  const size_t bh = (size_t)(b * 4 + h);
  const uint16_t* qtb = qt + bh * (32 * 1024);
  const uint16_t* kbp = kws + bh * (1024 * 32);
  const uint16_t* vtb = vt + bh * 65536 + (size_t)l * 8;  // lane-contiguous permuted V
  // Q^T B-fragment: B[kdim=8g+j][q=c], once per wave
  short8 qf;
  #pragma unroll
  for (int j = 0; j < 8; ++j) qf[j] = (short)qtb[(size_t)((g << 3) + j) * 1024 + nq];
  const int qrow = nq >> 5, qcol = nq & 31;
  // per-lane bias column offsets (keys 4g+r and 16+4g+r within a 32-key step)
  int dc0[4], dc1[4];
  #pragma unroll
  for (int r = 0; r < 4; ++r) {
    int a0 = qcol - ((g << 2) + r);      dc0[r] = a0 < 0 ? -a0 : a0;
    int a1 = qcol - (16 + (g << 2) + r); dc1[r] = a1 < 0 ? -a1 : a1;
  }

  f32x4 o0 = {0.f, 0.f, 0.f, 0.f}, o1 = o0, o2 = o0, o3 = o0;
  float l_run = 0.f;

  union U { uint4 u; short8 s; };
  for (int kb = 0, ts = 0; kb < 1024; kb += 32, ++ts) {
    // K A-fragments (fully coalesced): A[key=c][kdim=8g+j]
    U ka, kc;
    ka.u = *(const uint4*)(kbp + (size_t)(kb + c) * 32 + (g << 3));
    kc.u = *(const uint4*)(kbp + (size_t)(kb + 16 + c) * 32 + (g << 3));
    // V A-fragments (fully coalesced, wave reads 1KB contiguous per dt)
    const uint16_t* vp = vtb + (size_t)ts * 2048;
    U v0f, v1f, v2f, v3f;
    v0f.u = *(const uint4*)(vp);
    v1f.u = *(const uint4*)(vp + 512);
    v2f.u = *(const uint4*)(vp + 1024);
    v3f.u = *(const uint4*)(vp + 1536);

    const f32x4 z = {0.f, 0.f, 0.f, 0.f};
    f32x4 s0 = __builtin_amdgcn_mfma_f32_16x16x32_bf16(ka.s, qf, z, 0, 0, 0);
    f32x4 s1 = __builtin_amdgcn_mfma_f32_16x16x32_bf16(kc.s, qf, z, 0, 0, 0);

    // p = exp2(s*scale*l2e + bias*l2e); krow constant within step
    int dr = qrow - (kb >> 5); dr = dr < 0 ? -dr : dr;
    const float* brow = biasr + (dr << 5);
    float p[8];
    float sum = 0.f;
    #pragma unroll
    for (int r = 0; r < 4; ++r) {
      p[r]     = exp2f(fmaf(s0[r], SCALE2, brow[dc0[r]]));
      p[4 + r] = exp2f(fmaf(s1[r], SCALE2, brow[dc1[r]]));
      sum += p[r] + p[4 + r];
    }
    l_run += sum;
    // P^T B-fragment: this lane's own 8 p-values, same slot labeling as vt2
    U pf;
    pf.u = make_uint4(pk2(p[0], p[1]), pk2(p[2], p[3]), pk2(p[4], p[5]), pk2(p[6], p[7]));

    o0 = __builtin_amdgcn_mfma_f32_16x16x32_bf16(v0f.s, pf.s, o0, 0, 0, 0);
    o1 = __builtin_amdgcn_mfma_f32_16x16x32_bf16(v1f.s, pf.s, o1, 0, 0, 0);
    o2 = __builtin_amdgcn_mfma_f32_16x16x32_bf16(v2f.s, pf.s, o2, 0, 0, 0);
    o3 = __builtin_amdgcn_mfma_f32_16x16x32_bf16(v3f.s, pf.s, o3, 0, 0, 0);
  }

  float ls = l_run;
  ls += __shfl_xor(ls, 16, 64);
  ls += __shfl_xor(ls, 32, 64);
  const float inv = 1.f / ls;
  #pragma unroll
  for (int i = 0; i < 4; ++i) {
    osm[w][c][(g << 2) + i]      = o0[i] * inv;
    osm[w][c][16 + (g << 2) + i] = o1[i] * inv;
    osm[w][c][32 + (g << 2) + i] = o2[i] * inv;
    osm[w][c][48 + (g << 2) + i] = o3[i] * inv;
  }
  __syncthreads();
  const int q2 = l >> 2, dg = l & 3;
  const float4 r0 = *(const float4*)&osm[w][q2][dg * 16];
  const float4 r1 = *(const float4*)&osm[w][q2][dg * 16 + 4];
  const float4 r2 = *(const float4*)&osm[w][q2][dg * 16 + 8];
  const float4 r3 = *(const float4*)&osm[w][q2][dg * 16 + 12];
  float* op = ows + ((size_t)b * 1024 + (qb << 6) + (w << 4) + q2) * 256 + (h << 6) + dg * 16;
  *(float4*)(op)      = r0;
  *(float4*)(op + 4)  = r1;
  *(float4*)(op + 8)  = r2;
  *(float4*)(op + 12) = r3;
}

// ---------------- K3: x1 = x_in + BN(hardtanh(o) @ Wproj^T) ----------------
__global__ __launch_bounds__(256) void k3_proj(
    const float* __restrict__ ows, const float* __restrict__ x,
    const float* __restrict__ wt, const float* __restrict__ sh,
    float* __restrict__ x1) {
  __shared__ float os[256][36];
  const int t = threadIdx.x;
  const int b = blockIdx.x >> 5, n0 = (blockIdx.x & 31) << 5;
  {
    const int c0 = (t & 63) << 2;
    #pragma unroll
    for (int it = 0; it < 8; ++it) {
      const int j = (t >> 6) + (it << 2);
      float4 v4 = *(const float4*)(ows + ((size_t)b * 1024 + n0 + j) * 256 + c0);
      os[c0][j] = clip1(v4.x); os[c0 + 1][j] = clip1(v4.y);
      os[c0 + 2][j] = clip1(v4.z); os[c0 + 3][j] = clip1(v4.w);
    }
  }
  __syncthreads();
  const int d0 = (t & 31) << 2, j0 = (t >> 5) << 2;
  float acc[4][4];
  #pragma unroll
  for (int a = 0; a < 4; ++a)
    #pragma unroll
    for (int bb = 0; bb < 4; ++bb) acc[a][bb] = 0.f;
  for (int c2 = 0; c2 < 256; ++c2) {
    const float4 ov = *(const float4*)&os[c2][j0];
    const float4 wv = *(const float4*)(wt + c2 * 128 + d0);
    const float o_[4] = {ov.x, ov.y, ov.z, ov.w};
    const float w_[4] = {wv.x, wv.y, wv.z, wv.w};
    #pragma unroll
    for (int dd = 0; dd < 4; ++dd)
      #pragma unroll
      for (int jj = 0; jj < 4; ++jj)
        acc[dd][jj] = fmaf(w_[dd], o_[jj], acc[dd][jj]);
  }
  float res[4][4];
  #pragma unroll
  for (int dd = 0; dd < 4; ++dd) {
    const float shv = sh[d0 + dd];
    const float4 xv = *(const float4*)(x + ((size_t)b * 128 + d0 + dd) * 1024 + n0 + j0);
    res[dd][0] = acc[dd][0] + shv + xv.x;
    res[dd][1] = acc[dd][1] + shv + xv.y;
    res[dd][2] = acc[dd][2] + shv + xv.z;
    res[dd][3] = acc[dd][3] + shv + xv.w;
  }
  #pragma unroll
  for (int jj = 0; jj < 4; ++jj) {
    *(float4*)(x1 + ((size_t)b * 1024 + n0 + j0 + jj) * 128 + d0) =
        make_float4(res[0][jj], res[1][jj], res[2][jj], res[3][jj]);
  }
}

// ---------------- K4: h1 = hardtanh(BN(x1 @ Wf1^T)) -> bf16 ----------------
__global__ __launch_bounds__(256) void k4_f1(
    const float* __restrict__ x1, const float* __restrict__ wt, const float* __restrict__ sh,
    uint16_t* __restrict__ h1) {
  __shared__ float xs[128][36];
  const int t = threadIdx.x;
  const int b = blockIdx.x >> 5, n0 = (blockIdx.x & 31) << 5;
  {
    const int c0 = (t & 31) << 2;
    #pragma unroll
    for (int it = 0; it < 4; ++it) {
      const int j = (t >> 5) + (it << 3);
      float4 v4 = *(const float4*)(x1 + ((size_t)b * 1024 + n0 + j) * 128 + c0);
      xs[c0][j] = v4.x; xs[c0 + 1][j] = v4.y; xs[c0 + 2][j] = v4.z; xs[c0 + 3][j] = v4.w;
    }
  }
  __syncthreads();
  const int d0 = (t & 63) << 2, j0 = (t >> 6) << 3;
  float acc[4][8];
  #pragma unroll
  for (int a = 0; a < 4; ++a)
    #pragma unroll
    for (int bb = 0; bb < 8; ++bb) acc[a][bb] = 0.f;
  for (int c = 0; c < 128; ++c) {
    const float4 xa = *(const float4*)&xs[c][j0];
    const float4 xb = *(const float4*)&xs[c][j0 + 4];
    const float4 wv = *(const float4*)(wt + c * 256 + d0);
    const float xr[8] = {xa.x, xa.y, xa.z, xa.w, xb.x, xb.y, xb.z, xb.w};
    const float w_[4] = {wv.x, wv.y, wv.z, wv.w};
    #pragma unroll
    for (int dd = 0; dd < 4; ++dd)
      #pragma unroll
      for (int jj = 0; jj < 8; ++jj)
        acc[dd][jj] = fmaf(w_[dd], xr[jj], acc[dd][jj]);
  }
  float shr[4];
  #pragma unroll
  for (int dd = 0; dd < 4; ++dd) shr[dd] = sh[d0 + dd];
  #pragma unroll
  for (int jj = 0; jj < 8; ++jj) {
    const int n = n0 + j0 + jj;
    const float v0 = clip1(acc[0][jj] + shr[0]);
    const float v1 = clip1(acc[1][jj] + shr[1]);
    const float v2 = clip1(acc[2][jj] + shr[2]);
    const float v3 = clip1(acc[3][jj] + shr[3]);
    *(uint2*)(h1 + ((size_t)b * 1024 + n) * 256 + d0) = make_uint2(pk2(v0, v1), pk2(v2, v3));
  }
}

// ---------------- K5: out[b][c][n] = x1 + BN(h1 @ Wf2^T) ----------------
__global__ __launch_bounds__(256) void k5_f2(
    const uint16_t* __restrict__ h1, const float* __restrict__ x1,
    const float* __restrict__ wt, const float* __restrict__ sh,
    float* __restrict__ out) {
  __shared__ float hs[256][36];
  const int t = threadIdx.x;
  const int b = blockIdx.x >> 5, n0 = (blockIdx.x & 31) << 5;
  {
    const int c0 = (t & 31) << 3;
    #pragma unroll
    for (int it = 0; it < 4; ++it) {
      const int j = (t >> 5) + (it << 3);
      uint4 u = *(const uint4*)(h1 + ((size_t)b * 1024 + n0 + j) * 256 + c0);
      hs[c0][j] = lo16(u.x); hs[c0 + 1][j] = hi16(u.x);
      hs[c0 + 2][j] = lo16(u.y); hs[c0 + 3][j] = hi16(u.y);
      hs[c0 + 4][j] = lo16(u.z); hs[c0 + 5][j] = hi16(u.z);
      hs[c0 + 6][j] = lo16(u.w); hs[c0 + 7][j] = hi16(u.w);
    }
  }
  __syncthreads();
  const int d0 = (t & 31) << 2, j0 = (t >> 5) << 2;
  float acc[4][4];
  #pragma unroll
  for (int a = 0; a < 4; ++a)
    #pragma unroll
    for (int bb = 0; bb < 4; ++bb) acc[a][bb] = 0.f;
  for (int c2 = 0; c2 < 256; ++c2) {
    const float4 hv = *(const float4*)&hs[c2][j0];
    const float4 wv = *(const float4*)(wt + c2 * 128 + d0);
    const float h_[4] = {hv.x, hv.y, hv.z, hv.w};
    const float w_[4] = {wv.x, wv.y, wv.z, wv.w};
    #pragma unroll
    for (int dd = 0; dd < 4; ++dd)
      #pragma unroll
      for (int jj = 0; jj < 4; ++jj)
        acc[dd][jj] = fmaf(w_[dd], h_[jj], acc[dd][jj]);
  }
  float shr[4];
  #pragma unroll
  for (int dd = 0; dd < 4; ++dd) shr[dd] = sh[d0 + dd];
  float res[4][4];
  #pragma unroll
  for (int jj = 0; jj < 4; ++jj) {
    const float4 xv = *(const float4*)(x1 + ((size_t)b * 1024 + n0 + j0 + jj) * 128 + d0);
    res[0][jj] = acc[0][jj] + shr[0] + xv.x;
    res[1][jj] = acc[1][jj] + shr[1] + xv.y;
    res[2][jj] = acc[2][jj] + shr[2] + xv.z;
    res[3][jj] = acc[3][jj] + shr[3] + xv.w;
  }
  #pragma unroll
  for (int dd = 0; dd < 4; ++dd) {
    *(float4*)(out + ((size_t)b * 128 + d0 + dd) * 1024 + n0 + j0) =
        make_float4(res[dd][0], res[dd][1], res[dd][2], res[dd][3]);
  }
}

}  // namespace

extern "C" void kernel_launch(void* const* d_in, const int* in_sizes, int n_in,
                              void* d_out, int out_size, void* d_ws, size_t ws_size,
                              hipStream_t stream) {
  const float* x  = (const float*)d_in[0];
  const float* Wq = (const float*)d_in[1];
  const float* gq = (const float*)d_in[2];
  const float* bq = (const float*)d_in[3];
  const float* mq = (const float*)d_in[4];
  const float* vq = (const float*)d_in[5];
  const float* Wp = (const float*)d_in[6];
  const float* gp = (const float*)d_in[7];
  const float* bp = (const float*)d_in[8];
  const float* mp = (const float*)d_in[9];
  const float* vp = (const float*)d_in[10];
  const float* W1 = (const float*)d_in[11];
  const float* g1 = (const float*)d_in[12];
  const float* b1 = (const float*)d_in[13];
  const float* m1 = (const float*)d_in[14];
  const float* v1 = (const float*)d_in[15];
  const float* W2 = (const float*)d_in[16];
  const float* g2 = (const float*)d_in[17];
  const float* b2 = (const float*)d_in[18];
  const float* m2 = (const float*)d_in[19];
  const float* v2 = (const float*)d_in[20];
  const float* ab = (const float*)d_in[21];
  float* out = (float*)d_out;

  char* ws = (char*)d_ws;
  uint16_t* qt  = (uint16_t*)(ws);                 // 8 MiB  [bh][32][1024]
  uint16_t* kwsp= (uint16_t*)(ws + (8ull << 20));  // 8 MiB  [bh][1024][32]
  uint16_t* vt  = (uint16_t*)(ws + (16ull << 20)); // 16 MiB [bh][t][dt][g][c][j] permuted
  float*    ows = (float*)(ws + (32ull << 20));    // 32 MiB
  float*    x1  = (float*)(ws + (64ull << 20));    // 16 MiB
  uint16_t* h1  = (uint16_t*)(ws);                 // reuse qt/kws region (dead after K2)
  float* wqkvt = (float*)(ws + (80ull << 20));
  float* shq   = wqkvt + 65536;
  float* wpt   = shq + 512;
  float* shp   = wpt + 32768;
  float* w1t   = shp + 128;
  float* sh1   = w1t + 32768;
  float* w2t   = sh1 + 256;
  float* sh2   = w2t + 32768;

  k0_fold<<<644, 256, 0, stream>>>(Wq, gq, bq, mq, vq, Wp, gp, bp, mp, vp,
                                   W1, g1, b1, m1, v1, W2, g2, b2, m2, v2,
                                   wqkvt, shq, wpt, shp, w1t, sh1, w2t, sh2);
  k1_qkv<<<1024, 256, 0, stream>>>(x, wqkvt, shq, qt, kwsp, vt);
  k2_attn<<<2048, 256, 0, stream>>>(qt, kwsp, vt, ab, ows);
  k3_proj<<<1024, 256, 0, stream>>>(ows, x, wpt, shp, x1);
  k4_f1<<<1024, 256, 0, stream>>>(x1, w1t, sh1, h1);
  k5_f2<<<1024, 256, 0, stream>>>(h1, x1, w2t, sh2, out);
  (void)in_sizes; (void)n_in; (void)out_size; (void)ws_size;
}

// Round 5
// 166.495 us; speedup vs baseline: 2.7632x; 1.7201x over previous
//
#include <hip/hip_runtime.h>
#include <hip/hip_bf16.h>
#include <stdint.h>

namespace {

constexpr float EPSF = 1e-5f;
constexpr float L2E = 1.4426950408889634f;
constexpr float QK_SCALE = 0.17677669529663687f;  // 32^-0.5
constexpr float SCALE2 = QK_SCALE * L2E;          // folded for exp2

typedef __attribute__((ext_vector_type(8))) short short8;
typedef __attribute__((ext_vector_type(4))) float f32x4;

__device__ __forceinline__ uint32_t pk2(float a, float b) {  // RNE pair -> v_cvt_pk_bf16_f32
  union { __hip_bfloat162 h; uint32_t u; } cv;
  cv.h.x = __float2bfloat16(a);
  cv.h.y = __float2bfloat16(b);
  return cv.u;
}
__device__ __forceinline__ uint16_t bf1(float f) {
  union { __hip_bfloat16 h; uint16_t u; } cv;
  cv.h = __float2bfloat16(f);
  return cv.u;
}
__device__ __forceinline__ float clip1(float v) { return fminf(fmaxf(v, -1.f), 1.f); }

// ---------------- K0: fold BN scales into bf16 weights (row-major; w2 sigma-permuted) -------
// wqkvb[512][128], wpb[128][256], w1b[256][128],
// w2p[kk2:8][d2t:8][c:16][g:4][j:8] = W2fold[16*d2t+c][32*kk2 + (j<4 ? 4g+j : 16+4g+j-4)]
__global__ void k0_fold(
    const float* __restrict__ Wq, const float* __restrict__ gq, const float* __restrict__ bq,
    const float* __restrict__ mq, const float* __restrict__ vq,
    const float* __restrict__ Wp, const float* __restrict__ gp, const float* __restrict__ bp,
    const float* __restrict__ mp, const float* __restrict__ vp,
    const float* __restrict__ W1, const float* __restrict__ g1, const float* __restrict__ b1,
    const float* __restrict__ m1, const float* __restrict__ v1,
    const float* __restrict__ W2, const float* __restrict__ g2, const float* __restrict__ b2,
    const float* __restrict__ m2, const float* __restrict__ v2,
    uint16_t* __restrict__ wqkvb, float* __restrict__ shq,
    uint16_t* __restrict__ wpb, float* __restrict__ shp,
    uint16_t* __restrict__ w1b, float* __restrict__ sh1,
    uint16_t* __restrict__ w2p, float* __restrict__ sh2) {
  int id = blockIdx.x * 256 + threadIdx.x;
  if (id < 65536) {
    int d = id >> 7;
    wqkvb[id] = bf1(Wq[id] * (gq[d] * rsqrtf(vq[d] + EPSF)));
  } else if (id < 98304) {
    int j = id - 65536; int d = j >> 8;
    wpb[j] = bf1(Wp[j] * (gp[d] * rsqrtf(vp[d] + EPSF)));
  } else if (id < 131072) {
    int j = id - 98304; int d = j >> 7;
    w1b[j] = bf1(W1[j] * (g1[d] * rsqrtf(v1[d] + EPSF)));
  } else if (id < 163840) {
    int j = id - 131072;
    int jj = j & 7, g = (j >> 3) & 3, cc = (j >> 5) & 15, d2t = (j >> 9) & 7, kk2 = j >> 12;
    int d2 = d2t * 16 + cc;
    int d1 = kk2 * 32 + (jj < 4 ? 4 * g + jj : 16 + 4 * g + (jj - 4));
    w2p[j] = bf1(W2[d2 * 256 + d1] * (g2[d2] * rsqrtf(v2[d2] + EPSF)));
  } else if (id < 164864) {
    int j = id - 163840;
    if (j < 512)      shq[j] = bq[j] - mq[j] * (gq[j] * rsqrtf(vq[j] + EPSF));
    else if (j < 640) { int d = j - 512; shp[d] = bp[d] - mp[d] * (gp[d] * rsqrtf(vp[d] + EPSF)); }
    else if (j < 896) { int d = j - 640; sh1[d] = b1[d] - m1[d] * (g1[d] * rsqrtf(v1[d] + EPSF)); }
    else              { int d = j - 896; sh2[d] = b2[d] - m2[d] * (g2[d] * rsqrtf(v2[d] + EPSF)); }
  }
}

// ---------------- K1: MFMA qkv = BN(x_in @ Wqkv^T) -> qt / kws / vt2, bf16 ----------------
// block = 16 tokens, 4 waves; wave w == head w (128 out dims, 8 M-tiles x 4 K-steps).
// qt: [bh][32][1024]; kws: [bh][1024][32]; vt2: [bh][t][dt][g][c][j] sigma-permuted.
__global__ __launch_bounds__(256) void k1_qkv(
    const float* __restrict__ x, const uint16_t* __restrict__ wqkvb, const float* __restrict__ shq,
    uint16_t* __restrict__ qt, uint16_t* __restrict__ kws, uint16_t* __restrict__ vt) {
  __shared__ float xs[128][17];
  __shared__ uint16_t ys[4][16][132];
  const int t = threadIdx.x;
  const int blk = ((blockIdx.x & 7) << 8) | (blockIdx.x >> 3);  // bijective XCD chunk swizzle (2048)
  const int b = blk >> 6, n0 = (blk & 63) << 4;
  // stage x[b][:, n0..n0+15] -> xs[cdim][tok]
  {
    const int row = t >> 1, col = (t & 1) << 3;
    const float* xp = x + (size_t)b * (128 * 1024) + (size_t)row * 1024 + n0 + col;
    *(float4*)&xs[row][col] = *(const float4*)xp;
    *(float4*)&xs[row][col + 4] = *(const float4*)(xp + 4);
  }
  __syncthreads();
  const int w = t >> 6, l = t & 63, c = l & 15, g = l >> 4;
  union U { uint4 u; short8 s; };
  // B-frags: B[k=8g+j][tok=c] = x_in[tok][kdim], cvt f32->bf16
  U bf[4];
  #pragma unroll
  for (int kk = 0; kk < 4; ++kk) {
    const int k0i = kk * 32 + g * 8;
    bf[kk].u = make_uint4(pk2(xs[k0i][c], xs[k0i + 1][c]), pk2(xs[k0i + 2][c], xs[k0i + 3][c]),
                          pk2(xs[k0i + 4][c], xs[k0i + 5][c]), pk2(xs[k0i + 6][c], xs[k0i + 7][c]));
  }
  const int dbase = w << 7;
  #pragma unroll
  for (int dtl = 0; dtl < 8; ++dtl) {
    const uint16_t* ap = wqkvb + (size_t)(dbase + dtl * 16 + c) * 128 + g * 8;
    f32x4 acc = {0.f, 0.f, 0.f, 0.f};
    #pragma unroll
    for (int kk = 0; kk < 4; ++kk) {
      U a; a.u = *(const uint4*)(ap + kk * 32);
      acc = __builtin_amdgcn_mfma_f32_16x16x32_bf16(a.s, bf[kk].s, acc, 0, 0, 0);
    }
    const int dl = dtl * 16 + g * 4;
    *(uint32_t*)&ys[w][c][dl]     = pk2(acc[0] + shq[dbase + dl],     acc[1] + shq[dbase + dl + 1]);
    *(uint32_t*)&ys[w][c][dl + 2] = pk2(acc[2] + shq[dbase + dl + 2], acc[3] + shq[dbase + dl + 3]);
  }
  __syncthreads();
  const size_t bh = (size_t)(b * 4 + w);
  // K: local dims 32..63 -> kws row-major, fully coalesced
  {
    const int tok = l >> 2, seg = l & 3;
    const uint16_t* yp = &ys[w][tok][32 + seg * 8];
    *(uint4*)(kws + (bh * 1024 + n0 + tok) * 32 + seg * 8) =
        make_uint4(*(const uint32_t*)(yp), *(const uint32_t*)(yp + 2),
                   *(const uint32_t*)(yp + 4), *(const uint32_t*)(yp + 6));
  }
  // Q: local dims 0..31 -> qt transposed [dq][n]
  {
    const int dq = l >> 1, half = l & 1;
    uint32_t qv[4];
    #pragma unroll
    for (int i = 0; i < 4; ++i) {
      const uint32_t a0 = ys[w][half * 8 + 2 * i][dq];
      const uint32_t a1 = ys[w][half * 8 + 2 * i + 1][dq];
      qv[i] = (a0 & 0xFFFFu) | (a1 << 16);
    }
    *(uint4*)(qt + bh * 32768 + (size_t)dq * 1024 + n0 + half * 8) = make_uint4(qv[0], qv[1], qv[2], qv[3]);
  }
  // V: local dims 64..127 -> sigma-permuted vt2
  {
    const int cv = l & 15, gv = l >> 4;
    const int tb = (n0 >> 5) << 2;
    const int jb = (n0 & 16) ? 4 : 0;
    #pragma unroll
    for (int dtv = 0; dtv < 4; ++dtv) {
      const uint32_t v0 = ys[w][4 * gv + 0][64 + dtv * 16 + cv];
      const uint32_t v1 = ys[w][4 * gv + 1][64 + dtv * 16 + cv];
      const uint32_t v2 = ys[w][4 * gv + 2][64 + dtv * 16 + cv];
      const uint32_t v3 = ys[w][4 * gv + 3][64 + dtv * 16 + cv];
      *(uint2*)(vt + bh * 65536 + (size_t)(tb + dtv) * 512 + gv * 128 + cv * 8 + jb) =
          make_uint2((v0 & 0xFFFFu) | (v1 << 16), (v2 & 0xFFFFu) | (v3 << 16));
    }
  }
}

// ---------------- K2: MFMA flash attention -> ob = clip(o) bf16 [tok][256] ----------------
__global__ __launch_bounds__(256) void k2_attn(
    const uint16_t* __restrict__ qt, const uint16_t* __restrict__ kws,
    const uint16_t* __restrict__ vt, const float* __restrict__ ab,
    uint16_t* __restrict__ ob) {
  __shared__ float biasr[1024];
  __shared__ float osm[4][16][68];
  const int t = threadIdx.x;
  const int blk = ((blockIdx.x & 7) << 8) | (blockIdx.x >> 3);
  const int qb = blk & 15, h = (blk >> 4) & 3, b = blk >> 6;
  for (int i = t; i < 1024; i += 256) biasr[i] = ab[(h << 10) + i] * L2E;
  __syncthreads();
  const int w = t >> 6, l = t & 63;
  const int c = l & 15, g = l >> 4;
  const int nq = (qb << 6) + (w << 4) + c;
  const size_t bh = (size_t)(b * 4 + h);
  const uint16_t* qtb = qt + bh * (32 * 1024);
  const uint16_t* kbp = kws + bh * (1024 * 32);
  const uint16_t* vtb = vt + bh * 65536 + (size_t)l * 8;
  short8 qf;
  #pragma unroll
  for (int j = 0; j < 8; ++j) qf[j] = (short)qtb[(size_t)((g << 3) + j) * 1024 + nq];
  const int qrow = nq >> 5, qcol = nq & 31;
  int dc0[4], dc1[4];
  #pragma unroll
  for (int r = 0; r < 4; ++r) {
    int a0 = qcol - ((g << 2) + r);      dc0[r] = a0 < 0 ? -a0 : a0;
    int a1 = qcol - (16 + (g << 2) + r); dc1[r] = a1 < 0 ? -a1 : a1;
  }

  f32x4 o0 = {0.f, 0.f, 0.f, 0.f}, o1 = o0, o2 = o0, o3 = o0;
  float l_run = 0.f;

  union U { uint4 u; short8 s; };
  for (int kb = 0, ts = 0; kb < 1024; kb += 32, ++ts) {
    U ka, kc;
    ka.u = *(const uint4*)(kbp + (size_t)(kb + c) * 32 + (g << 3));
    kc.u = *(const uint4*)(kbp + (size_t)(kb + 16 + c) * 32 + (g << 3));
    const uint16_t* vp = vtb + (size_t)ts * 2048;
    U v0f, v1f, v2f, v3f;
    v0f.u = *(const uint4*)(vp);
    v1f.u = *(const uint4*)(vp + 512);
    v2f.u = *(const uint4*)(vp + 1024);
    v3f.u = *(const uint4*)(vp + 1536);

    const f32x4 z = {0.f, 0.f, 0.f, 0.f};
    f32x4 s0 = __builtin_amdgcn_mfma_f32_16x16x32_bf16(ka.s, qf, z, 0, 0, 0);
    f32x4 s1 = __builtin_amdgcn_mfma_f32_16x16x32_bf16(kc.s, qf, z, 0, 0, 0);

    int dr = qrow - (kb >> 5); dr = dr < 0 ? -dr : dr;
    const float* brow = biasr + (dr << 5);
    float p[8];
    float sum = 0.f;
    #pragma unroll
    for (int r = 0; r < 4; ++r) {
      p[r]     = exp2f(fmaf(s0[r], SCALE2, brow[dc0[r]]));
      p[4 + r] = exp2f(fmaf(s1[r], SCALE2, brow[dc1[r]]));
      sum += p[r] + p[4 + r];
    }
    l_run += sum;
    U pf;
    pf.u = make_uint4(pk2(p[0], p[1]), pk2(p[2], p[3]), pk2(p[4], p[5]), pk2(p[6], p[7]));

    o0 = __builtin_amdgcn_mfma_f32_16x16x32_bf16(v0f.s, pf.s, o0, 0, 0, 0);
    o1 = __builtin_amdgcn_mfma_f32_16x16x32_bf16(v1f.s, pf.s, o1, 0, 0, 0);
    o2 = __builtin_amdgcn_mfma_f32_16x16x32_bf16(v2f.s, pf.s, o2, 0, 0, 0);
    o3 = __builtin_amdgcn_mfma_f32_16x16x32_bf16(v3f.s, pf.s, o3, 0, 0, 0);
  }

  float ls = l_run;
  ls += __shfl_xor(ls, 16, 64);
  ls += __shfl_xor(ls, 32, 64);
  const float inv = 1.f / ls;
  #pragma unroll
  for (int i = 0; i < 4; ++i) {
    osm[w][c][(g << 2) + i]      = o0[i] * inv;
    osm[w][c][16 + (g << 2) + i] = o1[i] * inv;
    osm[w][c][32 + (g << 2) + i] = o2[i] * inv;
    osm[w][c][48 + (g << 2) + i] = o3[i] * inv;
  }
  __syncthreads();
  const int q2 = l >> 2, dg = l & 3;
  float ov[16];
  #pragma unroll
  for (int i = 0; i < 16; i += 4) {
    const float4 rr = *(const float4*)&osm[w][q2][dg * 16 + i];
    ov[i] = rr.x; ov[i + 1] = rr.y; ov[i + 2] = rr.z; ov[i + 3] = rr.w;
  }
  uint32_t pkd[8];
  #pragma unroll
  for (int i = 0; i < 8; ++i) pkd[i] = pk2(clip1(ov[2 * i]), clip1(ov[2 * i + 1]));
  uint16_t* opb = ob + ((size_t)b * 1024 + (qb << 6) + (w << 4) + q2) * 256 + (h << 6) + dg * 16;
  *(uint4*)(opb)     = make_uint4(pkd[0], pkd[1], pkd[2], pkd[3]);
  *(uint4*)(opb + 8) = make_uint4(pkd[4], pkd[5], pkd[6], pkd[7]);
}

// ---------------- K3: MFMA x1 = x_in + BN(ob @ Wproj^T) -> x1t f32 (ch-major) + x1b bf16 ----
// block = 64 tokens, 4 waves; wave w: 16 tokens, all 128 out dims (8 M-tiles x 8 K-steps).
__global__ __launch_bounds__(256) void k3_proj(
    const uint16_t* __restrict__ ob, const float* __restrict__ x,
    const uint16_t* __restrict__ wpb, const float* __restrict__ shp,
    float* __restrict__ x1t, uint16_t* __restrict__ x1b) {
  __shared__ uint16_t ys[4][16][132];
  const int t = threadIdx.x;
  const int b = blockIdx.x >> 4, n0 = (blockIdx.x & 15) << 6;
  const int w = t >> 6, l = t & 63, c = l & 15, g = l >> 4;
  const int tw = n0 + (w << 4) + c;
  union U { uint4 u; short8 s; };
  U bf[8];
  const uint16_t* op = ob + ((size_t)b * 1024 + tw) * 256 + g * 8;
  #pragma unroll
  for (int kk = 0; kk < 8; ++kk) bf[kk].u = *(const uint4*)(op + kk * 32);
  #pragma unroll
  for (int dt = 0; dt < 8; ++dt) {
    const uint16_t* ap = wpb + (size_t)(dt * 16 + c) * 256 + g * 8;
    f32x4 acc = {0.f, 0.f, 0.f, 0.f};
    #pragma unroll
    for (int kk = 0; kk < 8; ++kk) {
      U a; a.u = *(const uint4*)(ap + kk * 32);
      acc = __builtin_amdgcn_mfma_f32_16x16x32_bf16(a.s, bf[kk].s, acc, 0, 0, 0);
    }
    float vr[4];
    #pragma unroll
    for (int r = 0; r < 4; ++r) {
      const int d = dt * 16 + g * 4 + r;
      const size_t gi = ((size_t)b * 128 + d) * 1024 + tw;
      vr[r] = acc[r] + shp[d] + x[gi];
      x1t[gi] = vr[r];
    }
    const int dl = dt * 16 + g * 4;
    *(uint32_t*)&ys[w][c][dl]     = pk2(vr[0], vr[1]);
    *(uint32_t*)&ys[w][c][dl + 2] = pk2(vr[2], vr[3]);
  }
  __syncthreads();
  {
    const int tok = l & 15, q4 = l >> 4;
    uint32_t o2[16];
    #pragma unroll
    for (int i = 0; i < 16; ++i) o2[i] = *(const uint32_t*)&ys[w][tok][q4 * 32 + 2 * i];
    uint16_t* xb = x1b + ((size_t)b * 1024 + n0 + (w << 4) + tok) * 128 + q4 * 32;
    *(uint4*)(xb)      = make_uint4(o2[0], o2[1], o2[2], o2[3]);
    *(uint4*)(xb + 8)  = make_uint4(o2[4], o2[5], o2[6], o2[7]);
    *(uint4*)(xb + 16) = make_uint4(o2[8], o2[9], o2[10], o2[11]);
    *(uint4*)(xb + 24) = make_uint4(o2[12], o2[13], o2[14], o2[15]);
  }
}

// ---------------- K45: fused MLP, MFMA: out = x1 + BN(hardtanh(BN(x1@W1^T))@W2^T), ch-major --
// block = 64 tokens, 4 waves; h1 stays in registers (sigma slot-relabel, w2p pre-permuted).
__global__ __launch_bounds__(256) void k45_mlp(
    const uint16_t* __restrict__ x1b, const float* __restrict__ x1t,
    const uint16_t* __restrict__ w1b, const float* __restrict__ sh1,
    const uint16_t* __restrict__ w2p, const float* __restrict__ sh2,
    float* __restrict__ out) {
  const int t = threadIdx.x;
  const int b = blockIdx.x >> 4, n0 = (blockIdx.x & 15) << 6;
  const int w = t >> 6, l = t & 63, c = l & 15, g = l >> 4;
  const int tw = n0 + (w << 4) + c;
  union U { uint4 u; short8 s; };
  U xb[4];
  const uint16_t* xp = x1b + ((size_t)b * 1024 + tw) * 128 + g * 8;
  #pragma unroll
  for (int kk = 0; kk < 4; ++kk) xb[kk].u = *(const uint4*)(xp + kk * 32);
  float hh[16][4];
  #pragma unroll
  for (int dt1 = 0; dt1 < 16; ++dt1) {
    const uint16_t* ap = w1b + (size_t)(dt1 * 16 + c) * 128 + g * 8;
    f32x4 acc = {0.f, 0.f, 0.f, 0.f};
    #pragma unroll
    for (int kk = 0; kk < 4; ++kk) {
      U a; a.u = *(const uint4*)(ap + kk * 32);
      acc = __builtin_amdgcn_mfma_f32_16x16x32_bf16(a.s, xb[kk].s, acc, 0, 0, 0);
    }
    #pragma unroll
    for (int r = 0; r < 4; ++r) hh[dt1][r] = clip1(acc[r] + sh1[dt1 * 16 + g * 4 + r]);
  }
  U pf[8];
  #pragma unroll
  for (int kk2 = 0; kk2 < 8; ++kk2)
    pf[kk2].u = make_uint4(pk2(hh[2 * kk2][0], hh[2 * kk2][1]), pk2(hh[2 * kk2][2], hh[2 * kk2][3]),
                           pk2(hh[2 * kk2 + 1][0], hh[2 * kk2 + 1][1]), pk2(hh[2 * kk2 + 1][2], hh[2 * kk2 + 1][3]));
  #pragma unroll
  for (int d2t = 0; d2t < 8; ++d2t) {
    const uint16_t* ap = w2p + (size_t)(d2t * 16 + c) * 32 + g * 8;
    f32x4 acc = {0.f, 0.f, 0.f, 0.f};
    #pragma unroll
    for (int kk2 = 0; kk2 < 8; ++kk2) {
      U a; a.u = *(const uint4*)(ap + (size_t)kk2 * 4096);
      acc = __builtin_amdgcn_mfma_f32_16x16x32_bf16(a.s, pf[kk2].s, acc, 0, 0, 0);
    }
    #pragma unroll
    for (int r = 0; r < 4; ++r) {
      const int d = d2t * 16 + g * 4 + r;
      const size_t gi = ((size_t)b * 128 + d) * 1024 + tw;
      out[gi] = acc[r] + sh2[d] + x1t[gi];
    }
  }
}

}  // namespace

extern "C" void kernel_launch(void* const* d_in, const int* in_sizes, int n_in,
                              void* d_out, int out_size, void* d_ws, size_t ws_size,
                              hipStream_t stream) {
  const float* x  = (const float*)d_in[0];
  const float* Wq = (const float*)d_in[1];
  const float* gq = (const float*)d_in[2];
  const float* bq = (const float*)d_in[3];
  const float* mq = (const float*)d_in[4];
  const float* vq = (const float*)d_in[5];
  const float* Wp = (const float*)d_in[6];
  const float* gp = (const float*)d_in[7];
  const float* bp = (const float*)d_in[8];
  const float* mp = (const float*)d_in[9];
  const float* vp = (const float*)d_in[10];
  const float* W1 = (const float*)d_in[11];
  const float* g1 = (const float*)d_in[12];
  const float* b1 = (const float*)d_in[13];
  const float* m1 = (const float*)d_in[14];
  const float* v1 = (const float*)d_in[15];
  const float* W2 = (const float*)d_in[16];
  const float* g2 = (const float*)d_in[17];
  const float* b2 = (const float*)d_in[18];
  const float* m2 = (const float*)d_in[19];
  const float* v2 = (const float*)d_in[20];
  const float* ab = (const float*)d_in[21];
  float* out = (float*)d_out;

  char* ws = (char*)d_ws;
  uint16_t* qt   = (uint16_t*)(ws);                 // 8 MiB  [bh][32][1024]
  uint16_t* kwsp = (uint16_t*)(ws + (8ull << 20));  // 8 MiB  [bh][1024][32]
  uint16_t* vt   = (uint16_t*)(ws + (16ull << 20)); // 16 MiB sigma-permuted
  uint16_t* obuf = (uint16_t*)(ws + (32ull << 20)); // 16 MiB clip(o) bf16 [tok][256]
  float*    x1t  = (float*)(ws + (48ull << 20));    // 16 MiB f32 ch-major
  uint16_t* x1b  = (uint16_t*)(ws + (64ull << 20)); // 8 MiB bf16 [tok][128]
  uint16_t* wqkvb = (uint16_t*)(ws + (72ull << 20));
  uint16_t* wpb   = wqkvb + 65536;
  uint16_t* w1b   = wpb + 32768;
  uint16_t* w2p   = w1b + 32768;
  float* shq = (float*)(w2p + 32768);
  float* shp = shq + 512;
  float* sh1 = shp + 128;
  float* sh2 = sh1 + 256;

  k0_fold<<<644, 256, 0, stream>>>(Wq, gq, bq, mq, vq, Wp, gp, bp, mp, vp,
                                   W1, g1, b1, m1, v1, W2, g2, b2, m2, v2,
                                   wqkvb, shq, wpb, shp, w1b, sh1, w2p, sh2);
  k1_qkv<<<2048, 256, 0, stream>>>(x, wqkvb, shq, qt, kwsp, vt);
  k2_attn<<<2048, 256, 0, stream>>>(qt, kwsp, vt, ab, obuf);
  k3_proj<<<512, 256, 0, stream>>>(obuf, x, wpb, shp, x1t, x1b);
  k45_mlp<<<512, 256, 0, stream>>>(x1b, x1t, w1b, sh1, w2p, sh2, out);
  (void)in_sizes; (void)n_in; (void)out_size; (void)ws_size;
}